// Round 5
// baseline (318.610 us; speedup 1.0000x reference)
//
#include <hip/hip_runtime.h>

constexpr int BATCH = 8;
constexpr int CH    = 128;
constexpr int NPix  = 3072;          // 48*64
constexpr int NT    = 48;            // 64-pixel tiles per image
constexpr int NCHUNK = 4;            // split-m factor
constexpr int TPC   = NT / NCHUNK;   // tiles per chunk = 12
constexpr int MPC   = TPC * 64;      // m-values per chunk = 768
constexpr int TILE_SHORTS = 64 * CH; // 8192 bf16 per tile (16 KB)
constexpr float INV_SQRT_C = 0.08838834764831845f;
// exp(x*INV_SQRT_C) == exp2(x * INV_SQRT_C*log2(e)); fold the two muls into one.
constexpr float SC_EXP2 = 0.08838834764831845f * 1.4426950408889634f;

typedef __bf16 bf16x8 __attribute__((ext_vector_type(8)));
typedef float  floatx4 __attribute__((ext_vector_type(4)));

static __device__ __forceinline__ unsigned short f2bf(float f) {
  unsigned int u = __float_as_uint(f);
  u += 0x7fff + ((u >> 16) & 1);   // RNE
  return (unsigned short)(u >> 16);
}
static __device__ __forceinline__ float bf2f(unsigned short h) {
  return __uint_as_float((unsigned int)h << 16);
}

// Load a [CH][64] fp32 tile (ch-major) into LDS T[CH][65] from [B][CH][NPix].
static __device__ __forceinline__ void loadT(float (*T)[65],
                                             const float* __restrict__ src, int t) {
  const int cc = 4 * (t & 15);
  const int kb = t >> 4;
#pragma unroll
  for (int p = 0; p < 8; ++p) {
    const int k = kb + 16 * p;
    const float4 v = *(const float4*)(src + (size_t)k * NPix + cc);
    T[k][cc] = v.x; T[k][cc + 1] = v.y; T[k][cc + 2] = v.z; T[k][cc + 3] = v.w;
  }
}

// Stage one 16 KB fragment tile global -> LDS (256 thr x 4 uint4).
static __device__ __forceinline__ void stageK(unsigned short* __restrict__ dst,
                                              const unsigned short* __restrict__ src,
                                              int t) {
#pragma unroll
  for (int i = 0; i < 4; ++i)
    *(uint4*)&dst[(i * 256 + t) * 8] = *(const uint4*)(src + (size_t)(i * 256 + t) * 8);
}

// ---------------------------------------------------------------------------
// Merged setup: blocks 0..7 convert qw -> bf16 hi/lo B-frags; blocks 8..15
// each compute their own 16-row slice of W2 = kw@qw in LDS (same fmaf chain
// order as the original w2_kernel -> bit-identical), write b2, then convert
// their slice to w2b hi/lo frags.
// ---------------------------------------------------------------------------
__global__ __launch_bounds__(256) void setup_kernel(
    const float* __restrict__ qw, const float* __restrict__ qb,
    const float* __restrict__ kw, const float* __restrict__ kb,
    unsigned short* __restrict__ qwb_hi, unsigned short* __restrict__ qwb_lo,
    unsigned short* __restrict__ w2b_hi, unsigned short* __restrict__ w2b_lo,
    float* __restrict__ b2) {
  __shared__ float W2s[16][CH];
  const int t = threadIdx.x;
  const bool second = blockIdx.x >= 8;
  const int B = blockIdx.x & 7;
  if (second) {
#pragma unroll
    for (int p = 0; p < 8; ++p) {
      const int idx = p * 256 + t;
      const int r = idx >> 7, i = idx & 127;
      const int o = B * 16 + r;
      float acc = 0.f;
#pragma unroll 8
      for (int j = 0; j < CH; ++j)
        acc = fmaf(kw[o * CH + j], qw[j * CH + i], acc);
      W2s[r][i] = acc;
    }
    if (t < 16) {
      const int o = B * 16 + t;
      float a2 = kb[o];
#pragma unroll 8
      for (int j = 0; j < CH; ++j) a2 = fmaf(kw[o * CH + j], qb[j], a2);
      b2[o] = a2;
    }
    __syncthreads();
  }
  const int cidx = B * 256 + t;   // 0..2047
  const int l2 = cidx & 63, kc = (cidx >> 6) & 3;
  const int co = B * 16 + (l2 & 15);
  const int ci0 = kc * 32 + (l2 >> 4) * 8;
  unsigned short vh[8], vl[8];
#pragma unroll
  for (int j = 0; j < 8; ++j) {
    const float v = second ? W2s[l2 & 15][ci0 + j] : qw[co * CH + ci0 + j];
    const unsigned short h = f2bf(v);
    vh[j] = h;
    vl[j] = f2bf(v - bf2f(h));
  }
  *(uint4*)((second ? w2b_hi : qwb_hi) + (size_t)cidx * 8) = *(uint4*)vh;
  *(uint4*)((second ? w2b_lo : qwb_lo) + (size_t)cidx * 8) = *(uint4*)vl;
}

// ---------------------------------------------------------------------------
// Merged preprocessing.  (R8 verbatim.)
// ---------------------------------------------------------------------------
__global__ __launch_bounds__(256, 3) void preproc_kernel(
    const float* __restrict__ f0, const float* __restrict__ f1,
    const float* __restrict__ qb, const float* __restrict__ b2,
    const unsigned short* __restrict__ qwb_hi, const unsigned short* __restrict__ qwb_lo,
    const unsigned short* __restrict__ w2b_hi, const unsigned short* __restrict__ w2b_lo,
    unsigned short* __restrict__ f0t, unsigned short* __restrict__ f1t,
    unsigned short* __restrict__ qt, unsigned short* __restrict__ kt) {
  __shared__ float T[CH][65];
  const int t = threadIdx.x;
  const bool isF0 = blockIdx.x >= BATCH * NT;
  const int bi = blockIdx.x - (isF0 ? BATCH * NT : 0);
  const int b = bi / NT, tile = bi % NT;
  const size_t tb = (size_t)bi * TILE_SHORTS;

  loadT(T, (isF0 ? f0 : f1) + (size_t)b * CH * NPix + tile * 64, t);
  __syncthreads();

  unsigned short* gdst = (isF0 ? f0t : f1t) + tb;
#pragma unroll
  for (int i = 0; i < 4; ++i) {
    const int oi   = i * 256 + t;
    const int lane2 = oi & 63;
    const int kc   = (oi >> 6) & 3;
    const int c    = oi >> 8;
    const int r    = c * 16 + (lane2 & 15);
    const int ch0  = kc * 32 + (lane2 >> 4) * 8;
    unsigned short v[8];
#pragma unroll
    for (int j = 0; j < 8; ++j) v[j] = f2bf(T[ch0 + j][r]);
    *(uint4*)(gdst + (size_t)oi * 8) = *(uint4*)v;
  }
  if (!isF0) return;

  const int lane = t & 63, wave = t >> 6, quad = lane >> 4, lrow = lane & 15;

  bf16x8 ah[4], al[4];
#pragma unroll
  for (int kc = 0; kc < 4; ++kc) {
    unsigned short vh[8], vl[8];
#pragma unroll
    for (int j = 0; j < 8; ++j) {
      const float v = T[kc * 32 + quad * 8 + j][wave * 16 + lrow];
      const unsigned short h = f2bf(v);
      vh[j] = h;
      vl[j] = f2bf(v - bf2f(h));
    }
    ah[kc] = *(bf16x8*)vh;
    al[kc] = *(bf16x8*)vl;
  }

#pragma unroll
  for (int mat = 0; mat < 2; ++mat) {
    const unsigned short* wh = mat ? w2b_hi : qwb_hi;
    const unsigned short* wl = mat ? w2b_lo : qwb_lo;
    const float* bias = mat ? b2 : qb;
    unsigned short* dst = (mat ? kt : qt) + tb;
#pragma unroll
    for (int cb = 0; cb < 8; ++cb) {
      floatx4 acc = {0.f, 0.f, 0.f, 0.f};
#pragma unroll
      for (int kc = 0; kc < 4; ++kc) {
        const bf16x8 bh = *(const bf16x8*)(wh + ((cb * 4 + kc) * 64 + lane) * 8);
        const bf16x8 bl = *(const bf16x8*)(wl + ((cb * 4 + kc) * 64 + lane) * 8);
        acc = __builtin_amdgcn_mfma_f32_16x16x32_bf16(ah[kc], bh, acc, 0, 0, 0);
        acc = __builtin_amdgcn_mfma_f32_16x16x32_bf16(al[kc], bh, acc, 0, 0, 0);
        acc = __builtin_amdgcn_mfma_f32_16x16x32_bf16(ah[kc], bl, acc, 0, 0, 0);
      }
      const int co = cb * 16 + lrow;
      const float bv = bias[co];
      const int kcq = co >> 5, l2hi = ((co >> 3) & 3) * 16, j = co & 7;
#pragma unroll
      for (int r = 0; r < 4; ++r) {
        const int rl = quad * 4 + r;
        dst[((wave * 4 + kcq) * 64 + l2hi + rl) * 8 + j] = f2bf(acc[r] + bv);
      }
    }
  }
}

// ---------------------------------------------------------------------------
// Tile-paired, double-buffered flash corr (round-0 inner loop, un-hoisted).
// Last block of each 4-chunk group also emits flow_pred (threadFenceReduction
// pattern: release fence + device-scope atomicAdd; no dispatch-order
// assumption).
// ---------------------------------------------------------------------------
__global__ __launch_bounds__(256, 3) void corr_part_kernel(
    const unsigned short* __restrict__ f0t, const unsigned short* __restrict__ f1t,
    float* __restrict__ P, float* __restrict__ flow_pred,
    unsigned int* __restrict__ ctr) {
  __shared__ unsigned short Ks[2][TILE_SHORTS];
  __shared__ int isLast;
  const int t = threadIdx.x;
  const int b = blockIdx.x / ((NT / 2) * NCHUNK);
  const int rem = blockIdx.x % ((NT / 2) * NCHUNK);
  const int tp = rem >> 2, chunk = rem & 3;
  const int lane = t & 63, wave = t >> 6, quad = lane >> 4, lrow = lane & 15;

  bf16x8 af[2][4];
#pragma unroll
  for (int s = 0; s < 2; ++s) {
    const unsigned short* qp = f0t + (size_t)(b * NT + 2 * tp + s) * TILE_SHORTS;
#pragma unroll
    for (int kc = 0; kc < 4; ++kc)
      af[s][kc] = *(const bf16x8*)(qp + ((wave * 4 + kc) * 64 + lane) * 8);
  }

  float l[2][4] = {{0}}, sx[2][4] = {{0}}, sy[2][4] = {{0}};

  stageK(Ks[0], f1t + (size_t)(b * NT + chunk * TPC) * TILE_SHORTS, t);

  for (int mi = 0; mi < TPC; ++mi) {
    const int mt = chunk * TPC + mi;
    __syncthreads();
    if (mi + 1 < TPC)
      stageK(Ks[(mi + 1) & 1],
             f1t + (size_t)(b * NT + mt + 1) * TILE_SHORTS, t);
    const unsigned short* KB = Ks[mi & 1];

    float ts[2][4] = {{0}};
#pragma unroll
    for (int c = 0; c < 4; ++c) {
      const float x = (float)(c * 16 + lrow);
#pragma unroll
      for (int s = 0; s < 2; ++s) {
        floatx4 acc = {0.f, 0.f, 0.f, 0.f};
#pragma unroll
        for (int kc = 0; kc < 4; ++kc) {
          const bf16x8 bf = *(const bf16x8*)&KB[((c * 4 + kc) * 64 + lane) * 8];
          acc = __builtin_amdgcn_mfma_f32_16x16x32_bf16(af[s][kc], bf, acc, 0, 0, 0);
        }
#pragma unroll
        for (int r = 0; r < 4; ++r) {
          const float e = exp2f(acc[r] * SC_EXP2);
          ts[s][r] += e;
          sx[s][r] = fmaf(e, x, sx[s][r]);
        }
      }
    }
    const float y = (float)mt;
#pragma unroll
    for (int s = 0; s < 2; ++s)
#pragma unroll
      for (int r = 0; r < 4; ++r) {
        l[s][r] += ts[s][r];
        sy[s][r] = fmaf(y, ts[s][r], sy[s][r]);
      }
  }

#pragma unroll
  for (int off = 1; off < 16; off <<= 1)
#pragma unroll
    for (int s = 0; s < 2; ++s)
#pragma unroll
      for (int r = 0; r < 4; ++r) {
        l[s][r] += __shfl_xor(l[s][r], off);
        sx[s][r] += __shfl_xor(sx[s][r], off);
        sy[s][r] += __shfl_xor(sy[s][r], off);
      }
  if (lrow == 0) {
#pragma unroll
    for (int s = 0; s < 2; ++s)
#pragma unroll
      for (int r = 0; r < 4; ++r) {
        const int g = (b * NT + 2 * tp + s) * 64 + wave * 16 + quad * 4 + r;
        P[(g * 3 + 0) * 4 + chunk] = l[s][r];
        P[(g * 3 + 1) * 4 + chunk] = sx[s][r];
        P[(g * 3 + 2) * 4 + chunk] = sy[s][r];
      }
  }

  // ---- last block of the (b,tp) group reduces P -> flow_pred (128 rows) ----
  __syncthreads();
  if (t == 0) {
    __threadfence();   // release: make this block's P stores agent-visible
    isLast = (atomicAdd(&ctr[b * (NT / 2) + tp], 1u) == NCHUNK - 1);
  }
  __syncthreads();
  if (isLast) {
    __threadfence();   // acquire: see the other 3 chunks' P stores
    if (t < 128) {
      const int n = (2 * tp + (t >> 6)) * 64 + (t & 63);
      const int g = b * NPix + n;
      const float4 lv = *(const float4*)&P[(g * 3 + 0) * 4];
      const float4 xv = *(const float4*)&P[(g * 3 + 1) * 4];
      const float4 yv = *(const float4*)&P[(g * 3 + 2) * 4];
      const float lsum = (lv.x + lv.y) + (lv.z + lv.w);
      const float inv = 1.f / lsum;
      flow_pred[(size_t)(b * 2 + 0) * NPix + n] =
          ((xv.x + xv.y) + (xv.z + xv.w)) * inv - (float)(n & 63);
      flow_pred[(size_t)(b * 2 + 1) * NPix + n] =
          ((yv.x + yv.y) + (yv.z + yv.w)) * inv - (float)(n >> 6);
    }
  }
}

// ---------------------------------------------------------------------------
// Tile-paired, double-buffered fused attn (round-0 inner loop, un-hoisted).
// Last block of each 4-chunk group reduces P2 -> flow (replaces the separate
// reduce_attn kernel).
// ---------------------------------------------------------------------------
__global__ __launch_bounds__(256, 3) void attn_part_kernel(
    const unsigned short* __restrict__ qt, const unsigned short* __restrict__ kt,
    const float* __restrict__ P, float* __restrict__ P2,
    float* __restrict__ flow, unsigned int* __restrict__ ctr) {
  __shared__ unsigned short Ks[2][TILE_SHORTS];
  __shared__ float FP[MPC][2];
  __shared__ int isLast;
  const int t = threadIdx.x;
  const int b = blockIdx.x / ((NT / 2) * NCHUNK);
  const int rem = blockIdx.x % ((NT / 2) * NCHUNK);
  const int tp = rem >> 2, chunk = rem & 3;
  const int lane = t & 63, wave = t >> 6, quad = lane >> 4, lrow = lane & 15;

  for (int rr = t; rr < MPC; rr += 256) {
    const int n = chunk * MPC + rr;
    const int g = b * NPix + n;
    const float4 lv = *(const float4*)&P[(g * 3 + 0) * 4];
    const float4 xv = *(const float4*)&P[(g * 3 + 1) * 4];
    const float4 yv = *(const float4*)&P[(g * 3 + 2) * 4];
    const float lsum = (lv.x + lv.y) + (lv.z + lv.w);
    const float inv = 1.f / lsum;
    FP[rr][0] = ((xv.x + xv.y) + (xv.z + xv.w)) * inv - (float)(n & 63);
    FP[rr][1] = ((yv.x + yv.y) + (yv.z + yv.w)) * inv - (float)(n >> 6);
  }

  bf16x8 af[2][4];
#pragma unroll
  for (int s = 0; s < 2; ++s) {
    const unsigned short* qp = qt + (size_t)(b * NT + 2 * tp + s) * TILE_SHORTS;
#pragma unroll
    for (int kc = 0; kc < 4; ++kc)
      af[s][kc] = *(const bf16x8*)(qp + ((wave * 4 + kc) * 64 + lane) * 8);
  }

  float l[2][4] = {{0}}, sx[2][4] = {{0}}, sy[2][4] = {{0}};

  stageK(Ks[0], kt + (size_t)(b * NT + chunk * TPC) * TILE_SHORTS, t);

  for (int mi = 0; mi < TPC; ++mi) {
    const int mt = chunk * TPC + mi;
    __syncthreads();   // Ks[cur] staged + FP ready (first iter) + prior reads done
    if (mi + 1 < TPC)
      stageK(Ks[(mi + 1) & 1],
             kt + (size_t)(b * NT + mt + 1) * TILE_SHORTS, t);
    const unsigned short* KB = Ks[mi & 1];

#pragma unroll
    for (int c = 0; c < 4; ++c) {
      const int mloc = mi * 64 + c * 16 + lrow;
      const float vx = FP[mloc][0], vy = FP[mloc][1];
#pragma unroll
      for (int s = 0; s < 2; ++s) {
        floatx4 acc = {0.f, 0.f, 0.f, 0.f};
#pragma unroll
        for (int kc = 0; kc < 4; ++kc) {
          const bf16x8 bf = *(const bf16x8*)&KB[((c * 4 + kc) * 64 + lane) * 8];
          acc = __builtin_amdgcn_mfma_f32_16x16x32_bf16(af[s][kc], bf, acc, 0, 0, 0);
        }
#pragma unroll
        for (int r = 0; r < 4; ++r) {
          const float e = exp2f(acc[r] * SC_EXP2);
          l[s][r] += e;
          sx[s][r] = fmaf(e, vx, sx[s][r]);
          sy[s][r] = fmaf(e, vy, sy[s][r]);
        }
      }
    }
  }

#pragma unroll
  for (int off = 1; off < 16; off <<= 1)
#pragma unroll
    for (int s = 0; s < 2; ++s)
#pragma unroll
      for (int r = 0; r < 4; ++r) {
        l[s][r] += __shfl_xor(l[s][r], off);
        sx[s][r] += __shfl_xor(sx[s][r], off);
        sy[s][r] += __shfl_xor(sy[s][r], off);
      }
  if (lrow == 0) {
#pragma unroll
    for (int s = 0; s < 2; ++s)
#pragma unroll
      for (int r = 0; r < 4; ++r) {
        const int g = (b * NT + 2 * tp + s) * 64 + wave * 16 + quad * 4 + r;
        P2[(g * 3 + 0) * 4 + chunk] = l[s][r];
        P2[(g * 3 + 1) * 4 + chunk] = sx[s][r];
        P2[(g * 3 + 2) * 4 + chunk] = sy[s][r];
      }
  }

  // ---- last block of the (b,tp) group reduces P2 -> flow (128 rows) ----
  __syncthreads();
  if (t == 0) {
    __threadfence();
    isLast = (atomicAdd(&ctr[b * (NT / 2) + tp], 1u) == NCHUNK - 1);
  }
  __syncthreads();
  if (isLast) {
    __threadfence();
    if (t < 128) {
      const int n = (2 * tp + (t >> 6)) * 64 + (t & 63);
      const int g = b * NPix + n;
      const float4 lv = *(const float4*)&P2[(g * 3 + 0) * 4];
      const float4 xv = *(const float4*)&P2[(g * 3 + 1) * 4];
      const float4 yv = *(const float4*)&P2[(g * 3 + 2) * 4];
      const float lsum = (lv.x + lv.y) + (lv.z + lv.w);
      const float inv = 1.f / lsum;
      flow[(size_t)(b * 2 + 0) * NPix + n] = ((xv.x + xv.y) + (xv.z + xv.w)) * inv;
      flow[(size_t)(b * 2 + 1) * NPix + n] = ((yv.x + yv.y) + (yv.z + yv.w)) * inv;
    }
  }
}

// ---------------------------------------------------------------------------
extern "C" void kernel_launch(void* const* d_in, const int* in_sizes, int n_in,
                              void* d_out, int out_size, void* d_ws,
                              size_t ws_size, hipStream_t stream) {
  const float* f0  = (const float*)d_in[0];
  const float* f1  = (const float*)d_in[1];
  const float* q_w = (const float*)d_in[2];
  const float* q_b = (const float*)d_in[3];
  const float* k_w = (const float*)d_in[4];
  const float* k_b = (const float*)d_in[5];

  float* out       = (float*)d_out;
  float* flow      = out;                              // output 0
  float* flow_pred = out + (size_t)BATCH * 2 * NPix;   // output 1

  const size_t tile_elems = (size_t)BATCH * NT * TILE_SHORTS;
  unsigned short* f0t = (unsigned short*)d_ws;
  unsigned short* f1t = f0t + tile_elems;
  unsigned short* qt  = f1t + tile_elems;
  unsigned short* kt  = qt + tile_elems;
  unsigned short* qwb_hi = kt + tile_elems;     // 2048*8 bf16 each
  unsigned short* qwb_lo = qwb_hi + 2048 * 8;
  unsigned short* w2b_hi = qwb_lo + 2048 * 8;
  unsigned short* w2b_lo = w2b_hi + 2048 * 8;
  float* b2 = (float*)(w2b_lo + 2048 * 8);
  float* P  = b2 + CH;                       // 24576*12 floats
  float* P2 = P + (size_t)BATCH * NPix * 12;
  unsigned int* ctr = (unsigned int*)(P2 + (size_t)BATCH * NPix * 12);
  // 2 counter sets (corr groups, attn groups), 192 each; workspace is
  // re-poisoned between runs so they must be zeroed every launch.
  hipMemsetAsync(ctr, 0, 2 * BATCH * (NT / 2) * sizeof(unsigned int), stream);

  setup_kernel<<<16, 256, 0, stream>>>(q_w, q_b, k_w, k_b,
                                       qwb_hi, qwb_lo, w2b_hi, w2b_lo, b2);
  preproc_kernel<<<2 * BATCH * NT, 256, 0, stream>>>(
      f0, f1, q_b, b2, qwb_hi, qwb_lo, w2b_hi, w2b_lo, f0t, f1t, qt, kt);
  corr_part_kernel<<<BATCH * (NT / 2) * NCHUNK, 256, 0, stream>>>(
      f0t, f1t, P, flow_pred, ctr);
  attn_part_kernel<<<BATCH * (NT / 2) * NCHUNK, 256, 0, stream>>>(
      qt, kt, P, P2, flow, ctr + BATCH * (NT / 2));
}

// Round 7
// 175.626 us; speedup vs baseline: 1.8141x; 1.8141x over previous
//
#include <hip/hip_runtime.h>

constexpr int BATCH = 8;
constexpr int CH    = 128;
constexpr int NPix  = 3072;          // 48*64
constexpr int NT    = 48;            // 64-pixel tiles per image
constexpr int NCHUNK = 4;            // split-m factor
constexpr int TPC   = NT / NCHUNK;   // tiles per chunk = 12
constexpr int MPC   = TPC * 64;      // m-values per chunk = 768
constexpr int TILE_SHORTS = 64 * CH; // 8192 bf16 per tile (16 KB)
constexpr float INV_SQRT_C = 0.08838834764831845f;

typedef __bf16 bf16x8 __attribute__((ext_vector_type(8)));
typedef float  floatx4 __attribute__((ext_vector_type(4)));

static __device__ __forceinline__ unsigned short f2bf(float f) {
  unsigned int u = __float_as_uint(f);
  u += 0x7fff + ((u >> 16) & 1);   // RNE
  return (unsigned short)(u >> 16);
}
static __device__ __forceinline__ float bf2f(unsigned short h) {
  return __uint_as_float((unsigned int)h << 16);
}

// Load a [CH][64] fp32 tile (ch-major) into LDS T[CH][65] from [B][CH][NPix].
static __device__ __forceinline__ void loadT(float (*T)[65],
                                             const float* __restrict__ src, int t) {
  const int cc = 4 * (t & 15);
  const int kb = t >> 4;
#pragma unroll
  for (int p = 0; p < 8; ++p) {
    const int k = kb + 16 * p;
    const float4 v = *(const float4*)(src + (size_t)k * NPix + cc);
    T[k][cc] = v.x; T[k][cc + 1] = v.y; T[k][cc + 2] = v.z; T[k][cc + 3] = v.w;
  }
}

// ---------------------------------------------------------------------------
// W2 = kw @ qw, b2 = kw @ qb + kb.  (R0 verbatim.)
// ---------------------------------------------------------------------------
__global__ __launch_bounds__(256) void w2_kernel(
    const float* __restrict__ qw, const float* __restrict__ qb,
    const float* __restrict__ kw, const float* __restrict__ kb,
    float* __restrict__ W2, float* __restrict__ b2) {
  const int t = threadIdx.x;
  const int o = blockIdx.x * 2 + (t >> 7);
  const int i = t & 127;
  float acc = 0.f;
#pragma unroll 8
  for (int j = 0; j < CH; ++j)
    acc = fmaf(kw[o * CH + j], qw[j * CH + i], acc);
  W2[o * CH + i] = acc;
  if (i == 0) {
    float a2 = kb[o];
#pragma unroll 8
    for (int j = 0; j < CH; ++j) a2 = fmaf(kw[o * CH + j], qb[j], a2);
    b2[o] = a2;
  }
}

// ---------------------------------------------------------------------------
// qw / W2 fp32 -> bf16 B-frag hi/lo.  (R0 verbatim.)
// ---------------------------------------------------------------------------
__global__ __launch_bounds__(256) void wfrag_kernel(
    const float* __restrict__ qw, const float* __restrict__ W2,
    unsigned short* __restrict__ qwb_hi, unsigned short* __restrict__ qwb_lo,
    unsigned short* __restrict__ w2b_hi, unsigned short* __restrict__ w2b_lo) {
  const int t = threadIdx.x;
  const bool second = blockIdx.x >= 8;
  const int cidx = (blockIdx.x & 7) * 256 + t;   // 0..2047
  const int lane = cidx & 63, kc = (cidx >> 6) & 3, cb = cidx >> 8;
  const int co  = cb * 16 + (lane & 15);
  const int ci0 = kc * 32 + (lane >> 4) * 8;
  const float* src = (second ? W2 : qw) + co * CH + ci0;
  unsigned short vh[8], vl[8];
#pragma unroll
  for (int j = 0; j < 8; ++j) {
    const float v = src[j];
    const unsigned short h = f2bf(v);
    vh[j] = h;
    vl[j] = f2bf(v - bf2f(h));
  }
  *(uint4*)((second ? w2b_hi : qwb_hi) + (size_t)cidx * 8) = *(uint4*)vh;
  *(uint4*)((second ? w2b_lo : qwb_lo) + (size_t)cidx * 8) = *(uint4*)vl;
}

// ---------------------------------------------------------------------------
// Merged preprocessing.  (R0 verbatim.)
// ---------------------------------------------------------------------------
__global__ __launch_bounds__(256, 3) void preproc_kernel(
    const float* __restrict__ f0, const float* __restrict__ f1,
    const float* __restrict__ qb, const float* __restrict__ b2,
    const unsigned short* __restrict__ qwb_hi, const unsigned short* __restrict__ qwb_lo,
    const unsigned short* __restrict__ w2b_hi, const unsigned short* __restrict__ w2b_lo,
    unsigned short* __restrict__ f0t, unsigned short* __restrict__ f1t,
    unsigned short* __restrict__ qt, unsigned short* __restrict__ kt) {
  __shared__ float T[CH][65];
  const int t = threadIdx.x;
  const bool isF0 = blockIdx.x >= BATCH * NT;
  const int bi = blockIdx.x - (isF0 ? BATCH * NT : 0);
  const int b = bi / NT, tile = bi % NT;
  const size_t tb = (size_t)bi * TILE_SHORTS;

  loadT(T, (isF0 ? f0 : f1) + (size_t)b * CH * NPix + tile * 64, t);
  __syncthreads();

  unsigned short* gdst = (isF0 ? f0t : f1t) + tb;
#pragma unroll
  for (int i = 0; i < 4; ++i) {
    const int oi   = i * 256 + t;
    const int lane2 = oi & 63;
    const int kc   = (oi >> 6) & 3;
    const int c    = oi >> 8;
    const int r    = c * 16 + (lane2 & 15);
    const int ch0  = kc * 32 + (lane2 >> 4) * 8;
    unsigned short v[8];
#pragma unroll
    for (int j = 0; j < 8; ++j) v[j] = f2bf(T[ch0 + j][r]);
    *(uint4*)(gdst + (size_t)oi * 8) = *(uint4*)v;
  }
  if (!isF0) return;

  const int lane = t & 63, wave = t >> 6, quad = lane >> 4, lrow = lane & 15;

  bf16x8 ah[4], al[4];
#pragma unroll
  for (int kc = 0; kc < 4; ++kc) {
    unsigned short vh[8], vl[8];
#pragma unroll
    for (int j = 0; j < 8; ++j) {
      const float v = T[kc * 32 + quad * 8 + j][wave * 16 + lrow];
      const unsigned short h = f2bf(v);
      vh[j] = h;
      vl[j] = f2bf(v - bf2f(h));
    }
    ah[kc] = *(bf16x8*)vh;
    al[kc] = *(bf16x8*)vl;
  }

#pragma unroll
  for (int mat = 0; mat < 2; ++mat) {
    const unsigned short* wh = mat ? w2b_hi : qwb_hi;
    const unsigned short* wl = mat ? w2b_lo : qwb_lo;
    const float* bias = mat ? b2 : qb;
    unsigned short* dst = (mat ? kt : qt) + tb;
#pragma unroll
    for (int cb = 0; cb < 8; ++cb) {
      floatx4 acc = {0.f, 0.f, 0.f, 0.f};
#pragma unroll
      for (int kc = 0; kc < 4; ++kc) {
        const bf16x8 bh = *(const bf16x8*)(wh + ((cb * 4 + kc) * 64 + lane) * 8);
        const bf16x8 bl = *(const bf16x8*)(wl + ((cb * 4 + kc) * 64 + lane) * 8);
        acc = __builtin_amdgcn_mfma_f32_16x16x32_bf16(ah[kc], bh, acc, 0, 0, 0);
        acc = __builtin_amdgcn_mfma_f32_16x16x32_bf16(al[kc], bh, acc, 0, 0, 0);
        acc = __builtin_amdgcn_mfma_f32_16x16x32_bf16(ah[kc], bl, acc, 0, 0, 0);
      }
      const int co = cb * 16 + lrow;
      const float bv = bias[co];
      const int kcq = co >> 5, l2hi = ((co >> 3) & 3) * 16, j = co & 7;
#pragma unroll
      for (int r = 0; r < 4; ++r) {
        const int rl = quad * 4 + r;
        dst[((wave * 4 + kcq) * 64 + l2hi + rl) * 8 + j] = f2bf(acc[r] + bv);
      }
    }
  }
}

// ---------------------------------------------------------------------------
// Flash corr, LDS-staging-free: K fragments are read directly from global.
// Each 16 KB K-tile is reused by 24 blocks -> L2-resident (Common-mistake #7:
// don't LDS-stage what L2 already holds). No barriers in the main loop.
// Fragment bytes + MFMA order identical to R0 -> bit-identical P.
// ---------------------------------------------------------------------------
__global__ __launch_bounds__(256, 4) void corr_part_kernel(
    const unsigned short* __restrict__ f0t, const unsigned short* __restrict__ f1t,
    float* __restrict__ P) {
  const int t = threadIdx.x;
  const int b = blockIdx.x / ((NT / 2) * NCHUNK);
  const int rem = blockIdx.x % ((NT / 2) * NCHUNK);
  const int tp = rem >> 2, chunk = rem & 3;
  const int lane = t & 63, wave = t >> 6, quad = lane >> 4, lrow = lane & 15;

  bf16x8 af[2][4];
#pragma unroll
  for (int s = 0; s < 2; ++s) {
    const unsigned short* qp = f0t + (size_t)(b * NT + 2 * tp + s) * TILE_SHORTS;
#pragma unroll
    for (int kc = 0; kc < 4; ++kc)
      af[s][kc] = *(const bf16x8*)(qp + ((wave * 4 + kc) * 64 + lane) * 8);
  }

  float l[2][4] = {{0}}, sx[2][4] = {{0}}, sy[2][4] = {{0}};

  for (int mi = 0; mi < TPC; ++mi) {
    const int mt = chunk * TPC + mi;
    const unsigned short* KB = f1t + (size_t)(b * NT + mt) * TILE_SHORTS;

    float ts[2][4] = {{0}};
#pragma unroll
    for (int c = 0; c < 4; ++c) {
      const float x = (float)(c * 16 + lrow);
#pragma unroll
      for (int s = 0; s < 2; ++s) {
        floatx4 acc = {0.f, 0.f, 0.f, 0.f};
#pragma unroll
        for (int kc = 0; kc < 4; ++kc) {
          const bf16x8 bf = *(const bf16x8*)&KB[((c * 4 + kc) * 64 + lane) * 8];
          acc = __builtin_amdgcn_mfma_f32_16x16x32_bf16(af[s][kc], bf, acc, 0, 0, 0);
        }
#pragma unroll
        for (int r = 0; r < 4; ++r) {
          const float e = __expf(acc[r] * INV_SQRT_C);
          ts[s][r] += e;
          sx[s][r] = fmaf(e, x, sx[s][r]);
        }
      }
    }
    const float y = (float)mt;
#pragma unroll
    for (int s = 0; s < 2; ++s)
#pragma unroll
      for (int r = 0; r < 4; ++r) {
        l[s][r] += ts[s][r];
        sy[s][r] = fmaf(y, ts[s][r], sy[s][r]);
      }
  }

#pragma unroll
  for (int off = 1; off < 16; off <<= 1)
#pragma unroll
    for (int s = 0; s < 2; ++s)
#pragma unroll
      for (int r = 0; r < 4; ++r) {
        l[s][r] += __shfl_xor(l[s][r], off);
        sx[s][r] += __shfl_xor(sx[s][r], off);
        sy[s][r] += __shfl_xor(sy[s][r], off);
      }
  if (lrow == 0) {
#pragma unroll
    for (int s = 0; s < 2; ++s)
#pragma unroll
      for (int r = 0; r < 4; ++r) {
        const int g = (b * NT + 2 * tp + s) * 64 + wave * 16 + quad * 4 + r;
        P[(g * 3 + 0) * 4 + chunk] = l[s][r];
        P[(g * 3 + 1) * 4 + chunk] = sx[s][r];
        P[(g * 3 + 2) * 4 + chunk] = sy[s][r];
      }
  }
}

// ---------------------------------------------------------------------------
// Flash attn, LDS-staging-free (same rationale).  FP stays in LDS (6 KB).
// One barrier after the FP fill; none in the main loop.
// ---------------------------------------------------------------------------
__global__ __launch_bounds__(256, 4) void attn_part_kernel(
    const unsigned short* __restrict__ qt, const unsigned short* __restrict__ kt,
    const float* __restrict__ P, float* __restrict__ flow_pred,
    float* __restrict__ P2) {
  __shared__ float FP[MPC][2];
  const int t = threadIdx.x;
  const int b = blockIdx.x / ((NT / 2) * NCHUNK);
  const int rem = blockIdx.x % ((NT / 2) * NCHUNK);
  const int tp = rem >> 2, chunk = rem & 3;
  const int lane = t & 63, wave = t >> 6, quad = lane >> 4, lrow = lane & 15;

  for (int rr = t; rr < MPC; rr += 256) {
    const int n = chunk * MPC + rr;
    const int g = b * NPix + n;
    const float4 lv = *(const float4*)&P[(g * 3 + 0) * 4];
    const float4 xv = *(const float4*)&P[(g * 3 + 1) * 4];
    const float4 yv = *(const float4*)&P[(g * 3 + 2) * 4];
    const float lsum = (lv.x + lv.y) + (lv.z + lv.w);
    const float inv = 1.f / lsum;
    FP[rr][0] = ((xv.x + xv.y) + (xv.z + xv.w)) * inv - (float)(n & 63);
    FP[rr][1] = ((yv.x + yv.y) + (yv.z + yv.w)) * inv - (float)(n >> 6);
  }
  __syncthreads();   // FP complete before main-loop reads / flow_pred write

  if (tp == 0) {
    for (int rr = t; rr < MPC; rr += 256) {
      const int n = chunk * MPC + rr;
      flow_pred[(size_t)(b * 2 + 0) * NPix + n] = FP[rr][0];
      flow_pred[(size_t)(b * 2 + 1) * NPix + n] = FP[rr][1];
    }
  }

  bf16x8 af[2][4];
#pragma unroll
  for (int s = 0; s < 2; ++s) {
    const unsigned short* qp = qt + (size_t)(b * NT + 2 * tp + s) * TILE_SHORTS;
#pragma unroll
    for (int kc = 0; kc < 4; ++kc)
      af[s][kc] = *(const bf16x8*)(qp + ((wave * 4 + kc) * 64 + lane) * 8);
  }

  float l[2][4] = {{0}}, sx[2][4] = {{0}}, sy[2][4] = {{0}};

  for (int mi = 0; mi < TPC; ++mi) {
    const int mt = chunk * TPC + mi;
    const unsigned short* KB = kt + (size_t)(b * NT + mt) * TILE_SHORTS;

#pragma unroll
    for (int c = 0; c < 4; ++c) {
      const int mloc = mi * 64 + c * 16 + lrow;
      const float vx = FP[mloc][0], vy = FP[mloc][1];
#pragma unroll
      for (int s = 0; s < 2; ++s) {
        floatx4 acc = {0.f, 0.f, 0.f, 0.f};
#pragma unroll
        for (int kc = 0; kc < 4; ++kc) {
          const bf16x8 bf = *(const bf16x8*)&KB[((c * 4 + kc) * 64 + lane) * 8];
          acc = __builtin_amdgcn_mfma_f32_16x16x32_bf16(af[s][kc], bf, acc, 0, 0, 0);
        }
#pragma unroll
        for (int r = 0; r < 4; ++r) {
          const float e = __expf(acc[r] * INV_SQRT_C);
          l[s][r] += e;
          sx[s][r] = fmaf(e, vx, sx[s][r]);
          sy[s][r] = fmaf(e, vy, sy[s][r]);
        }
      }
    }
  }

#pragma unroll
  for (int off = 1; off < 16; off <<= 1)
#pragma unroll
    for (int s = 0; s < 2; ++s)
#pragma unroll
      for (int r = 0; r < 4; ++r) {
        l[s][r] += __shfl_xor(l[s][r], off);
        sx[s][r] += __shfl_xor(sx[s][r], off);
        sy[s][r] += __shfl_xor(sy[s][r], off);
      }
  if (lrow == 0) {
#pragma unroll
    for (int s = 0; s < 2; ++s)
#pragma unroll
      for (int r = 0; r < 4; ++r) {
        const int g = (b * NT + 2 * tp + s) * 64 + wave * 16 + quad * 4 + r;
        P2[(g * 3 + 0) * 4 + chunk] = l[s][r];
        P2[(g * 3 + 1) * 4 + chunk] = sx[s][r];
        P2[(g * 3 + 2) * 4 + chunk] = sy[s][r];
      }
  }
}

__global__ __launch_bounds__(256) void reduce_attn_kernel(
    const float* __restrict__ P2, float* __restrict__ flow) {
  const int g = blockIdx.x * 256 + threadIdx.x;  // 0..24575
  const float4 lv = *(const float4*)&P2[(g * 3 + 0) * 4];
  const float4 xv = *(const float4*)&P2[(g * 3 + 1) * 4];
  const float4 yv = *(const float4*)&P2[(g * 3 + 2) * 4];
  const float l = (lv.x + lv.y) + (lv.z + lv.w);
  const float inv = 1.f / l;
  const int b = g / NPix, n = g % NPix;
  flow[(size_t)(b * 2 + 0) * NPix + n] = ((xv.x + xv.y) + (xv.z + xv.w)) * inv;
  flow[(size_t)(b * 2 + 1) * NPix + n] = ((yv.x + yv.y) + (yv.z + yv.w)) * inv;
}

// ---------------------------------------------------------------------------
extern "C" void kernel_launch(void* const* d_in, const int* in_sizes, int n_in,
                              void* d_out, int out_size, void* d_ws,
                              size_t ws_size, hipStream_t stream) {
  const float* f0  = (const float*)d_in[0];
  const float* f1  = (const float*)d_in[1];
  const float* q_w = (const float*)d_in[2];
  const float* q_b = (const float*)d_in[3];
  const float* k_w = (const float*)d_in[4];
  const float* k_b = (const float*)d_in[5];

  float* out       = (float*)d_out;
  float* flow      = out;                              // output 0
  float* flow_pred = out + (size_t)BATCH * 2 * NPix;   // output 1

  const size_t tile_elems = (size_t)BATCH * NT * TILE_SHORTS;
  unsigned short* f0t = (unsigned short*)d_ws;
  unsigned short* f1t = f0t + tile_elems;
  unsigned short* qt  = f1t + tile_elems;
  unsigned short* kt  = qt + tile_elems;
  unsigned short* qwb_hi = kt + tile_elems;     // 2048*8 bf16 each
  unsigned short* qwb_lo = qwb_hi + 2048 * 8;
  unsigned short* w2b_hi = qwb_lo + 2048 * 8;
  unsigned short* w2b_lo = w2b_hi + 2048 * 8;
  float* W2 = (float*)(w2b_lo + 2048 * 8);
  float* b2 = W2 + CH * CH;
  float* P  = b2 + CH;                       // 24576*12 floats
  float* P2 = P + (size_t)BATCH * NPix * 12;

  w2_kernel<<<64, 256, 0, stream>>>(q_w, q_b, k_w, k_b, W2, b2);
  wfrag_kernel<<<16, 256, 0, stream>>>(q_w, W2, qwb_hi, qwb_lo, w2b_hi, w2b_lo);
  preproc_kernel<<<2 * BATCH * NT, 256, 0, stream>>>(
      f0, f1, q_b, b2, qwb_hi, qwb_lo, w2b_hi, w2b_lo, f0t, f1t, qt, kt);
  corr_part_kernel<<<BATCH * (NT / 2) * NCHUNK, 256, 0, stream>>>(f0t, f1t, P);
  attn_part_kernel<<<BATCH * (NT / 2) * NCHUNK, 256, 0, stream>>>(qt, kt, P,
                                                                  flow_pred, P2);
  reduce_attn_kernel<<<96, 256, 0, stream>>>(P2, flow);
}